// Round 9
// baseline (1269.350 us; speedup 1.0000x reference)
//
#include <hip/hip_runtime.h>
#include <hip/hip_bf16.h>
#include <math.h>
#include <stdint.h>

// Problem constants
#define CCH   192      // channels
#define HWD   224      // H = W = 224
#define NWIN  8192     // 8 * 32 * 32 windows
#define NPIX  49       // 7*7 pixels per window
#define KDIM  192      // GEMM1 K
#define NHEAD 6
#define ROWB  (KDIM * 2)   // 384 bytes per LDS row
#define NW    8            // windows per block (consecutive ww, same row)
#define NBLK  (NWIN / NW)  // 1024 blocks = exactly 2 rounds at 2 blocks/CU

typedef __bf16 bf16x8 __attribute__((ext_vector_type(8)));
typedef __bf16 bf16x2 __attribute__((ext_vector_type(2)));
typedef float  f32x4  __attribute__((ext_vector_type(4)));

// Convert W (384x192 f32) to bf16 pre-swizzled into MFMA B-fragment order:
// out[((ng*6 + kk)*4 + lg)*128 + lr*8 + e] = W[(ng*16+lr)*192 + kk*32+lg*8+e]
__global__ void wconv_kernel(const float* __restrict__ w,
                             uint16_t* __restrict__ wbf) {
    int o = blockIdx.x * 256 + threadIdx.x;
    if (o >= 384 * 192) return;
    int e  = o & 7;
    int t  = o >> 3;
    int lr = t & 15;  t >>= 4;
    int lg = t & 3;   t >>= 2;
    int kk = t % 6;
    int ng = t / 6;
    int col  = ng * 16 + lr;
    int kcol = kk * 32 + lg * 8 + e;
    __bf16 v = (__bf16)w[col * KDIM + kcol];
    wbf[o] = __builtin_bit_cast(uint16_t, v);
}

// 8 windows per block, 512 threads = 8 waves.
// LDS: x-ping + x-pong + k = 3 x 49x192 bf16 = 56448 B -> 2 blocks/CU.
// Cross-window prefetch: gather chunk A of window j+1 is issued before
// GEMM1(j) (drains at the post-GEMM1 barrier), chunk B at phase-4 start
// (drains at loop-end barrier) — both covered by MFMA/softmax compute.
// ((512,8)/(512,6) force spills — R5/R6; real footprint ~112 unified regs.)
__global__ __launch_bounds__(512, 4)
void attn_win_kernel(const float* __restrict__ x,
                     const uint16_t* __restrict__ wbf,
                     const float* __restrict__ bq,
                     float* __restrict__ out) {
    __shared__ uint16_t bufX[NPIX * KDIM];   // x ping (xw, later q)
    __shared__ uint16_t bufY[NPIX * KDIM];   // x pong (xw, later q)
    __shared__ uint16_t bufK[NPIX * KDIM];   // k

    const int tid  = threadIdx.x;
    const int wave = tid >> 6;   // 0..7
    const int l    = tid & 63;
    const int lg   = l >> 4;     // 0..3
    const int lr   = l & 15;     // 0..15

    // XCD-contiguous remap: XCD i owns batch image i (1024 blocks % 8 == 0)
    const int blk  = (int)blockIdx.x;
    const int blk2 = (blk & 7) * (NBLK / 8) + (blk >> 3);
    const int wbase = blk2 * NW;             // 8 consecutive windows, same row
    const int b    = wbase >> 10;
    const int wh   = (wbase >> 5) & 31;
    const int ww0  = wbase & 31;             // in {0,8,16,24}; ww0+7 <= 31
    const int h0   = wh * 7;

    // lane gather geometry (lane = pixel, wave owns 24 channels)
    const int pr = (l * 37) >> 8;            // l / 7 for l in [0,49)
    const int ps = l - pr * 7;
    const float* xlane = x + (size_t)(b * CCH + wave * 24) * (HWD * HWD)
                           + (size_t)(h0 + pr) * HWD + ps;   // + c*HWD*HWD + w0
    const uint32_t rb  = (uint32_t)(l * ROWB + wave * 48);   // + c*2
    const uint32_t swz = (uint32_t)((l & 7) << 4);
    const bool glane = (l < NPIX);

    // ---- Prologue: gather window 0 -> bufX
    if (glane) {
        const float* xp = xlane + (size_t)(ww0 * 7);
        #pragma unroll
        for (int c = 0; c < 24; c += 2) {
            float v0 = xp[(size_t)c * (HWD * HWD)];
            float v1 = xp[(size_t)(c + 1) * (HWD * HWD)];
            bf16x2 p = { (__bf16)v0, (__bf16)v1 };
            *(uint32_t*)((char*)bufX + ((rb + (uint32_t)(c * 2)) ^ swz)) =
                __builtin_bit_cast(uint32_t, p);
        }
    }
    __syncthreads();

    uint16_t* xc = bufX;
    uint16_t* xn = bufY;

    for (int j = 0; j < NW; ++j) {
        const bool pf = (j + 1 < NW) && glane;
        const float* xpn = xlane + (size_t)((ww0 + j + 1) * 7); // next window

        // issue prefetch chunk A (channels 0..11 of window j+1)
        float ga[12];
        if (pf) {
            #pragma unroll
            for (int c = 0; c < 12; ++c)
                ga[c] = xpn[(size_t)c * (HWD * HWD)];
        }

        // ---- GEMM1  qk[64 x 384] = xw @ W^T   (wave owns 48 W-cols)
        f32x4 acc[4][3];
        #pragma unroll
        for (int mt = 0; mt < 4; ++mt)
            #pragma unroll
            for (int nt = 0; nt < 3; ++nt)
                acc[mt][nt] = f32x4{0.f, 0.f, 0.f, 0.f};

        #pragma unroll
        for (int kk = 0; kk < 6; ++kk) {
            bf16x8 afr[4];
            #pragma unroll
            for (int mt = 0; mt < 4; ++mt) {
                int row = mt * 16 + lr;
                if (row > 48) row = 48;                    // clamp: no pad rows
                int byte = (row * ROWB + kk * 64 + lg * 16) ^ ((row & 7) << 4);
                afr[mt] = *(const bf16x8*)((const char*)xc + byte);
            }
            #pragma unroll
            for (int nt = 0; nt < 3; ++nt) {
                int ng = wave * 3 + nt;
                bf16x8 bfr = *(const bf16x8*)(wbf + ((ng * 6 + kk) * 4 + lg) * 128 + lr * 8);
                #pragma unroll
                for (int mt = 0; mt < 4; ++mt)
                    acc[mt][nt] = __builtin_amdgcn_mfma_f32_16x16x32_bf16(
                        afr[mt], bfr, acc[mt][nt], 0, 0, 0);
            }
        }
        __syncthreads();   // B1: GEMM1 reads of xc done (drains ga loads)

        // write chunk A -> xn (channel c at byte offset c*2)
        if (pf) {
            #pragma unroll
            for (int c = 0; c < 12; c += 2) {
                bf16x2 p = { (__bf16)ga[c], (__bf16)ga[c + 1] };
                *(uint32_t*)((char*)xn + ((rb + (uint32_t)(c * 2)) ^ swz)) =
                    __builtin_bit_cast(uint32_t, p);
            }
        }

        // ---- Phase 3: bias (+scale*log2e for q), q -> xc, k -> bufK (bf16)
        {
            const float mulq = 0.2550348616845977f;  // 32^-0.5 * log2(e)
            const bool isq = (wave < 4);
            const float mul = isq ? mulq : 1.0f;
            uint16_t* dst = isq ? xc : bufK;
            #pragma unroll
            for (int nt = 0; nt < 3; ++nt) {
                int colW = wave * 48 + nt * 16 + lr;    // 0..383
                float bias = bq[colW];
                int jj = isq ? colW : (colW - 192);
                #pragma unroll
                for (int mt = 0; mt < 4; ++mt) {
                    #pragma unroll
                    for (int r = 0; r < 4; ++r) {
                        int row = mt * 16 + lg * 4 + r;
                        if (row < NPIX) {
                            __bf16 bv = (__bf16)((acc[mt][nt][r] + bias) * mul);
                            *(__bf16*)((char*)dst +
                                ((row * ROWB + jj * 2) ^ ((row & 7) << 4))) = bv;
                        }
                    }
                }
            }
        }
        __syncthreads();   // B2: q/k visible to all waves

        // issue prefetch chunk B (channels 12..23 of window j+1);
        // covered by phase 4 compute, drains at B3 (loop end)
        float gb[12];
        if (pf) {
            #pragma unroll
            for (int c = 0; c < 12; ++c)
                gb[c] = xpn[(size_t)(12 + c) * (HWD * HWD)];
        }

        // ---- Phase 4: swapped-operand GEMM2 + lane-local softmax + stores.
        // mfma(K_tile, Q_tile): D col = q-row, D row = k-idx. Lane (lg,lr) of
        // wave (qt = wave&3) holds S[qrow = qt*16+lr][k = nt2*16 + lg*4 + r].
        float* outw = out + (size_t)(wbase + j) * (NHEAD * NPIX * NPIX);
        const int qt    = wave & 3;
        const int hbase = wave >> 2;
        const int qrow  = qt * 16 + lr;
        const int qrc   = qrow > 48 ? 48 : qrow;            // clamped read row
        const uint32_t qswz = (uint32_t)((qrc & 7) << 4);

        for (int hi = 0; hi < 3; ++hi) {
            const int h = hbase + hi * 2;
            const bf16x8 qfr = *(const bf16x8*)((const char*)xc +
                (((uint32_t)(qrc * ROWB + h * 64 + lg * 16)) ^ qswz));

            float v[16];
            #pragma unroll
            for (int nt2 = 0; nt2 < 4; ++nt2) {
                int krow = nt2 * 16 + lr;
                if (krow > 48) krow = 48;                   // clamp
                const bf16x8 kfr = *(const bf16x8*)((const char*)bufK +
                    (((uint32_t)(krow * ROWB + h * 64 + lg * 16)) ^ ((krow & 7) << 4)));
                f32x4 p = __builtin_amdgcn_mfma_f32_16x16x32_bf16(
                    kfr, qfr, f32x4{0.f, 0.f, 0.f, 0.f}, 0, 0, 0);
                #pragma unroll
                for (int r = 0; r < 4; ++r) {
                    int k = nt2 * 16 + lg * 4 + r;
                    v[nt2 * 4 + r] = (k < NPIX) ? p[r] : -INFINITY;
                }
            }

            // row softmax: 16 in-lane values + 2 cross-lane steps
            float m = v[0];
            #pragma unroll
            for (int i = 1; i < 16; ++i) m = fmaxf(m, v[i]);
            m = fmaxf(m, __shfl_xor(m, 16, 64));
            m = fmaxf(m, __shfl_xor(m, 32, 64));

            float sum = 0.f;
            #pragma unroll
            for (int i = 0; i < 16; ++i) {
                v[i] = exp2f(v[i] - m);    // logits already in log2 domain
                sum += v[i];
            }
            sum += __shfl_xor(sum, 16, 64);
            sum += __shfl_xor(sum, 32, 64);
            const float inv = __fdividef(1.0f, sum);

            if (qrow < NPIX) {
                float* orow = outw + h * (NPIX * NPIX) + qrow * NPIX;
                #pragma unroll
                for (int nt2 = 0; nt2 < 3; ++nt2)
                    #pragma unroll
                    for (int r = 0; r < 4; ++r)
                        orow[nt2 * 16 + lg * 4 + r] = v[nt2 * 4 + r] * inv;
                if (lg == 0) orow[48] = v[12] * inv;
            }
        }

        // write chunk B -> xn (channel 12+c at byte offset (12+c)*2;
        // R8 bug was (24+c)*2 — landed in the next wave's strip)
        if (pf) {
            #pragma unroll
            for (int c = 0; c < 12; c += 2) {
                bf16x2 p = { (__bf16)gb[c], (__bf16)gb[c + 1] };
                *(uint32_t*)((char*)xn + ((rb + (uint32_t)((12 + c) * 2)) ^ swz)) =
                    __builtin_bit_cast(uint32_t, p);
            }
        }
        __syncthreads();   // B3: xn complete + q/k reads done for next window

        uint16_t* t = xc; xc = xn; xn = t;
    }
}

extern "C" void kernel_launch(void* const* d_in, const int* in_sizes, int n_in,
                              void* d_out, int out_size, void* d_ws, size_t ws_size,
                              hipStream_t stream) {
    const float* x  = (const float*)d_in[0];
    const float* W  = (const float*)d_in[1];
    const float* bq = (const float*)d_in[2];
    float* out = (float*)d_out;
    uint16_t* wbf = (uint16_t*)d_ws;   // 384*192 bf16 = 147456 B (swizzled)

    wconv_kernel<<<(384 * 192 + 255) / 256, 256, 0, stream>>>(W, wbf);
    attn_win_kernel<<<NBLK, 512, 0, stream>>>(x, wbf, bq, out);
}

// Round 10
// 327.233 us; speedup vs baseline: 3.8790x; 3.8790x over previous
//
#include <hip/hip_runtime.h>
#include <hip/hip_bf16.h>
#include <math.h>
#include <stdint.h>

// Problem constants
#define CCH   192      // channels
#define HWD   224      // H = W = 224
#define NWIN  8192     // 8 * 32 * 32 windows
#define NPIX  49       // 7*7 pixels per window
#define KDIM  192      // GEMM1 K
#define NHEAD 6
#define ROWB  (KDIM * 2)   // 384 bytes per LDS row

typedef __bf16 bf16x8 __attribute__((ext_vector_type(8)));
typedef __bf16 bf16x2 __attribute__((ext_vector_type(2)));
typedef float  f32x4  __attribute__((ext_vector_type(4)));

// Convert W (384x192 f32) to bf16 pre-swizzled into MFMA B-fragment order:
// out[((ng*6 + kk)*4 + lg)*128 + lr*8 + e] = W[(ng*16+lr)*192 + kk*32+lg*8+e]
__global__ void wconv_kernel(const float* __restrict__ w,
                             uint16_t* __restrict__ wbf) {
    int o = blockIdx.x * 256 + threadIdx.x;
    if (o >= 384 * 192) return;
    int e  = o & 7;
    int t  = o >> 3;
    int lr = t & 15;  t >>= 4;
    int lg = t & 3;   t >>= 2;
    int kk = t % 6;
    int ng = t / 6;
    int col  = ng * 16 + lr;
    int kcol = kk * 32 + lg * 8 + e;
    __bf16 v = (__bf16)w[col * KDIM + kcol];
    wbf[o] = __builtin_bit_cast(uint16_t, v);
}

// One block per window, 1024 threads = 16 waves.
// acc[2][3] (24 regs) instead of acc[4][3]: 16 waves cover the 96 GEMM1
// tiles, so per-wave footprint fits the 64-reg budget of 8 waves/SIMD ->
// 2 blocks/CU = 32 waves/CU (100% occupancy). LDS = 2 x 49x192 bf16 = 37888 B.
// (R5/R6/R9: the acc[4][3] variant is pinned at 4 waves/SIMD; every attempt
// to add waves or prefetch regs on top of it spilled to scratch.)
__global__ __launch_bounds__(1024, 8)
void attn_win_kernel(const float* __restrict__ x,
                     const uint16_t* __restrict__ wbf,
                     const float* __restrict__ bq,
                     float* __restrict__ out) {
    __shared__ uint16_t ldsA[NPIX * KDIM];   // xw tile, later q
    __shared__ uint16_t ldsB[NPIX * KDIM];   // k

    const int tid  = threadIdx.x;
    const int wave = tid >> 6;   // 0..15
    const int l    = tid & 63;
    const int lg   = l >> 4;     // 0..3
    const int lr   = l & 15;     // 0..15

    // XCD-bijective remap: each XCD gets one contiguous batch image (8192 % 8 == 0)
    const int win = ((blockIdx.x & 7) << 10) | (blockIdx.x >> 3);
    const int b   = win >> 10;
    const int wh  = (win >> 5) & 31;
    const int ww  = win & 31;
    const int h0 = wh * 7, w0 = ww * 7;

    // ---- Phase 1: gather x window -> ldsA (bf16, XOR-swizzled rows).
    // lane = pixel (49 active), wave owns 12 channels; pack 2 chans per u32.
    if (l < NPIX) {
        int r = (l * 37) >> 8;          // l / 7 for l in [0,49)
        int s = l - r * 7;
        const float* xp = x + (size_t)(b * CCH + wave * 12) * (HWD * HWD)
                            + (h0 + r) * HWD + (w0 + s);
        const uint32_t rb  = (uint32_t)(l * ROWB + wave * 24);
        const uint32_t swz = (uint32_t)((l & 7) << 4);
        #pragma unroll
        for (int c = 0; c < 12; c += 2) {
            float v0 = xp[0];
            float v1 = xp[HWD * HWD];
            xp += 2 * (HWD * HWD);
            bf16x2 p = { (__bf16)v0, (__bf16)v1 };
            uint32_t byte = (rb + (uint32_t)(c * 2)) ^ swz;
            *(uint32_t*)((char*)ldsA + byte) = __builtin_bit_cast(uint32_t, p);
        }
    }
    __syncthreads();

    // ---- Phase 2: GEMM1  qk[64 x 384] = xw @ W^T
    // wave = (mp, cg): rows mp*32..mp*32+31, cols cg*48..cg*48+47.
    const int mp = wave & 1;
    const int cg = wave >> 1;    // 0..7
    f32x4 acc[2][3];
    #pragma unroll
    for (int mt = 0; mt < 2; ++mt)
        #pragma unroll
        for (int nt = 0; nt < 3; ++nt)
            acc[mt][nt] = f32x4{0.f, 0.f, 0.f, 0.f};

    #pragma unroll
    for (int kk = 0; kk < 6; ++kk) {
        bf16x8 afr[2];
        #pragma unroll
        for (int mt = 0; mt < 2; ++mt) {
            int row = mp * 32 + mt * 16 + lr;
            if (row > 48) row = 48;                       // clamp: no pad rows
            int byte = (row * ROWB + kk * 64 + lg * 16) ^ ((row & 7) << 4);
            afr[mt] = *(const bf16x8*)((const char*)ldsA + byte);
        }
        #pragma unroll
        for (int nt = 0; nt < 3; ++nt) {
            int ng = cg * 3 + nt;
            bf16x8 bfr = *(const bf16x8*)(wbf + ((ng * 6 + kk) * 4 + lg) * 128 + lr * 8);
            #pragma unroll
            for (int mt = 0; mt < 2; ++mt)
                acc[mt][nt] = __builtin_amdgcn_mfma_f32_16x16x32_bf16(
                    afr[mt], bfr, acc[mt][nt], 0, 0, 0);
        }
    }
    __syncthreads();   // all GEMM1 reads of ldsA done before q overwrites it

    // ---- Phase 3: bias (+scale*log2e for q), q -> ldsA, k -> ldsB (bf16)
    {
        const float mulq = 0.2550348616845977f;  // 32^-0.5 * log2(e)
        const bool isq = (cg < 4);
        const float mul = isq ? mulq : 1.0f;
        uint16_t* dst = isq ? ldsA : ldsB;
        #pragma unroll
        for (int nt = 0; nt < 3; ++nt) {
            int colW = cg * 48 + nt * 16 + lr;    // 0..383
            float bias = bq[colW];
            int jj = isq ? colW : (colW - 192);
            #pragma unroll
            for (int mt = 0; mt < 2; ++mt) {
                #pragma unroll
                for (int r = 0; r < 4; ++r) {
                    int row = mp * 32 + mt * 16 + lg * 4 + r;
                    if (row < NPIX) {
                        __bf16 bv = (__bf16)((acc[mt][nt][r] + bias) * mul);
                        *(__bf16*)((char*)dst +
                            ((row * ROWB + jj * 2) ^ ((row & 7) << 4))) = bv;
                    }
                }
            }
        }
    }
    __syncthreads();

    // ---- Phase 4: swapped-operand GEMM2 + lane-local softmax + direct stores.
    // mfma(K_tile, Q_tile): D col = q-row, D row = k-idx. Lane (lg,lr) of wave
    // (qt = wave&3) holds S[qrow = qt*16+lr][k = nt2*16 + lg*4 + r].
    // 24 (head,qt) pairs over 16 waves: wave w does head w>>2 (0..3), and
    // waves 0-7 also do head (w>>2)+4. Imbalance is free: kernel ends here,
    // single-head waves simply retire early.
    float* outw = out + (size_t)win * (NHEAD * NPIX * NPIX);
    const int qt    = wave & 3;
    const int qrow  = qt * 16 + lr;
    const int qrc   = qrow > 48 ? 48 : qrow;            // clamped read row
    const uint32_t qswz = (uint32_t)((qrc & 7) << 4);

    auto do_head = [&](int h) {
        const bf16x8 qfr = *(const bf16x8*)((const char*)ldsA +
            (((uint32_t)(qrc * ROWB + h * 64 + lg * 16)) ^ qswz));

        float v[16];
        #pragma unroll
        for (int nt2 = 0; nt2 < 4; ++nt2) {
            int krow = nt2 * 16 + lr;
            if (krow > 48) krow = 48;                   // clamp (masked later)
            const bf16x8 kfr = *(const bf16x8*)((const char*)ldsB +
                (((uint32_t)(krow * ROWB + h * 64 + lg * 16)) ^ ((krow & 7) << 4)));
            f32x4 p = __builtin_amdgcn_mfma_f32_16x16x32_bf16(
                kfr, qfr, f32x4{0.f, 0.f, 0.f, 0.f}, 0, 0, 0);
            #pragma unroll
            for (int r = 0; r < 4; ++r) {
                int k = nt2 * 16 + lg * 4 + r;
                v[nt2 * 4 + r] = (k < NPIX) ? p[r] : -INFINITY;
            }
        }

        // row softmax: 16 in-lane values + 2 cross-lane steps (l^16, l^32)
        float m = v[0];
        #pragma unroll
        for (int i = 1; i < 16; ++i) m = fmaxf(m, v[i]);
        m = fmaxf(m, __shfl_xor(m, 16, 64));
        m = fmaxf(m, __shfl_xor(m, 32, 64));

        float sum = 0.f;
        #pragma unroll
        for (int i = 0; i < 16; ++i) {
            v[i] = exp2f(v[i] - m);    // logits already in log2 domain
            sum += v[i];
        }
        sum += __shfl_xor(sum, 16, 64);
        sum += __shfl_xor(sum, 32, 64);
        const float inv = __fdividef(1.0f, sum);

        if (qrow < NPIX) {
            float* orow = outw + h * (NPIX * NPIX) + qrow * NPIX;
            #pragma unroll
            for (int nt2 = 0; nt2 < 3; ++nt2)
                #pragma unroll
                for (int r = 0; r < 4; ++r)
                    orow[nt2 * 16 + lg * 4 + r] = v[nt2 * 4 + r] * inv;
            if (lg == 0) orow[48] = v[12] * inv;
        }
    };

    const int h1 = wave >> 2;      // 0..3
    do_head(h1);
    if (wave < 8) do_head(h1 + 4); // heads 4,5
}

extern "C" void kernel_launch(void* const* d_in, const int* in_sizes, int n_in,
                              void* d_out, int out_size, void* d_ws, size_t ws_size,
                              hipStream_t stream) {
    const float* x  = (const float*)d_in[0];
    const float* W  = (const float*)d_in[1];
    const float* bq = (const float*)d_in[2];
    float* out = (float*)d_out;
    uint16_t* wbf = (uint16_t*)d_ws;   // 384*192 bf16 = 147456 B (swizzled)

    wconv_kernel<<<(384 * 192 + 255) / 256, 256, 0, stream>>>(W, wbf);
    attn_win_kernel<<<NWIN, 1024, 0, stream>>>(x, wbf, bq, out);
}

// Round 11
// 317.062 us; speedup vs baseline: 4.0035x; 1.0321x over previous
//
#include <hip/hip_runtime.h>
#include <hip/hip_bf16.h>
#include <math.h>
#include <stdint.h>

// Problem constants
#define CCH   192      // channels
#define HWD   224      // H = W = 224
#define NWIN  8192     // 8 * 32 * 32 windows
#define NPIX  49       // 7*7 pixels per window
#define KDIM  192      // GEMM1 K
#define NHEAD 6
#define ROWB  (KDIM * 2)   // 384 bytes per LDS row
#define MULQ  0.2550348616845977f   // 32^-0.5 * log2(e), folded into W_q/b_q

typedef __bf16 bf16x8 __attribute__((ext_vector_type(8)));
typedef __bf16 bf16x2 __attribute__((ext_vector_type(2)));
typedef float  f32x4  __attribute__((ext_vector_type(4)));

// Convert W (384x192 f32) to bf16 pre-swizzled into MFMA B-fragment order,
// with scale*log2e pre-folded into the q half (rows 0..191).
// out[((ng*6 + kk)*4 + lg)*128 + lr*8 + e] = W[(ng*16+lr)*192 + kk*32+lg*8+e]
// Also writes the (scaled) bias as f32 at wbf+73728 (byte offset 147456).
__global__ void wconv_kernel(const float* __restrict__ w,
                             const float* __restrict__ bq,
                             uint16_t* __restrict__ wbf) {
    int o = blockIdx.x * 256 + threadIdx.x;
    if (o >= 384 * 192) return;
    if (o < 384) {
        float bb = bq[o];
        if (o < 192) bb *= MULQ;
        ((float*)(wbf + 384 * 192))[o] = bb;
    }
    int e  = o & 7;
    int t  = o >> 3;
    int lr = t & 15;  t >>= 4;
    int lg = t & 3;   t >>= 2;
    int kk = t % 6;
    int ng = t / 6;
    int col  = ng * 16 + lr;
    int kcol = kk * 32 + lg * 8 + e;
    float wv = w[col * KDIM + kcol];
    if (col < 192) wv *= MULQ;            // q half pre-scaled
    __bf16 v = (__bf16)wv;
    wbf[o] = __builtin_bit_cast(uint16_t, v);
}

// One block per window, 1024 threads = 16 waves, 2 blocks/CU (32 waves, max).
// R10 structure + this round: (a) gather loads hoisted (1 HBM latency, not 6),
// (b) bias pre-loaded into the MFMA accumulator (C/D col=lr, bias is col-only
// -> splat is exact), (c) scale*log2e folded into W_q/b_q at wconv time, so
// phase 3 is a bare f32->bf16 cvt + LDS write.
__global__ __launch_bounds__(1024, 8)
void attn_win_kernel(const float* __restrict__ x,
                     const uint16_t* __restrict__ wbf,
                     float* __restrict__ out) {
    __shared__ uint16_t ldsA[NPIX * KDIM];   // xw tile, later q
    __shared__ uint16_t ldsB[NPIX * KDIM];   // k

    const int tid  = threadIdx.x;
    const int wave = tid >> 6;   // 0..15
    const int l    = tid & 63;
    const int lg   = l >> 4;     // 0..3
    const int lr   = l & 15;     // 0..15

    // XCD-bijective remap: each XCD gets one contiguous batch image (8192 % 8 == 0)
    const int win = ((blockIdx.x & 7) << 10) | (blockIdx.x >> 3);
    const int b   = win >> 10;
    const int wh  = (win >> 5) & 31;
    const int ww  = win & 31;
    const int h0 = wh * 7, w0 = ww * 7;

    const float* bias = (const float*)(wbf + 384 * 192);

    // ---- Phase 1: gather x window -> ldsA (bf16, XOR-swizzled rows).
    // lane = pixel (49 active), wave owns 12 channels. All 12 loads issued
    // before any LDS write (single exposed HBM latency; regs are phase-local).
    if (l < NPIX) {
        int r = (l * 37) >> 8;          // l / 7 for l in [0,49)
        int s = l - r * 7;
        const float* xp = x + (size_t)(b * CCH + wave * 12) * (HWD * HWD)
                            + (h0 + r) * HWD + (w0 + s);
        float g[12];
        #pragma unroll
        for (int c = 0; c < 12; ++c)
            g[c] = xp[(size_t)c * (HWD * HWD)];
        const uint32_t rb  = (uint32_t)(l * ROWB + wave * 24);
        const uint32_t swz = (uint32_t)((l & 7) << 4);
        #pragma unroll
        for (int c = 0; c < 12; c += 2) {
            bf16x2 p = { (__bf16)g[c], (__bf16)g[c + 1] };
            uint32_t byte = (rb + (uint32_t)(c * 2)) ^ swz;
            *(uint32_t*)((char*)ldsA + byte) = __builtin_bit_cast(uint32_t, p);
        }
    }
    __syncthreads();

    // ---- Phase 2: GEMM1  qk[64 x 384] = xw @ W^T (+bias via acc init)
    // wave = (mp, cg): rows mp*32..mp*32+31, cols cg*48..cg*48+47.
    const int mp = wave & 1;
    const int cg = wave >> 1;    // 0..7
    f32x4 acc[2][3];
    #pragma unroll
    for (int nt = 0; nt < 3; ++nt) {
        float bb = bias[cg * 48 + nt * 16 + lr];   // col = lr across all 4 regs
        #pragma unroll
        for (int mt = 0; mt < 2; ++mt)
            acc[mt][nt] = f32x4{bb, bb, bb, bb};
    }

    #pragma unroll
    for (int kk = 0; kk < 6; ++kk) {
        bf16x8 afr[2];
        #pragma unroll
        for (int mt = 0; mt < 2; ++mt) {
            int row = mp * 32 + mt * 16 + lr;
            if (row > 48) row = 48;                       // clamp: no pad rows
            int byte = (row * ROWB + kk * 64 + lg * 16) ^ ((row & 7) << 4);
            afr[mt] = *(const bf16x8*)((const char*)ldsA + byte);
        }
        #pragma unroll
        for (int nt = 0; nt < 3; ++nt) {
            int ng = cg * 3 + nt;
            bf16x8 bfr = *(const bf16x8*)(wbf + ((ng * 6 + kk) * 4 + lg) * 128 + lr * 8);
            #pragma unroll
            for (int mt = 0; mt < 2; ++mt)
                acc[mt][nt] = __builtin_amdgcn_mfma_f32_16x16x32_bf16(
                    afr[mt], bfr, acc[mt][nt], 0, 0, 0);
        }
    }
    __syncthreads();   // all GEMM1 reads of ldsA done before q overwrites it

    // ---- Phase 3: q -> ldsA, k -> ldsB (bf16); bias/scale already applied
    {
        const bool isq = (cg < 4);
        uint16_t* dst = isq ? ldsA : ldsB;
        #pragma unroll
        for (int nt = 0; nt < 3; ++nt) {
            int colW = cg * 48 + nt * 16 + lr;    // 0..383
            int jj = isq ? colW : (colW - 192);
            #pragma unroll
            for (int mt = 0; mt < 2; ++mt) {
                #pragma unroll
                for (int r = 0; r < 4; ++r) {
                    int row = mp * 32 + mt * 16 + lg * 4 + r;
                    if (row < NPIX) {
                        __bf16 bv = (__bf16)acc[mt][nt][r];
                        *(__bf16*)((char*)dst +
                            ((row * ROWB + jj * 2) ^ ((row & 7) << 4))) = bv;
                    }
                }
            }
        }
    }
    __syncthreads();

    // ---- Phase 4: swapped-operand GEMM2 + lane-local softmax + direct stores.
    // mfma(K_tile, Q_tile): D col = q-row, D row = k-idx. Lane (lg,lr) of wave
    // (qt = wave&3) holds S[qrow = qt*16+lr][k = nt2*16 + lg*4 + r].
    // 24 (head,qt) pairs over 16 waves: wave w does head w>>2 (0..3), and
    // waves 0-7 also do head (w>>2)+4.
    float* outw = out + (size_t)win * (NHEAD * NPIX * NPIX);
    const int qt    = wave & 3;
    const int qrow  = qt * 16 + lr;
    const int qrc   = qrow > 48 ? 48 : qrow;            // clamped read row
    const uint32_t qswz = (uint32_t)((qrc & 7) << 4);

    auto do_head = [&](int h) {
        const bf16x8 qfr = *(const bf16x8*)((const char*)ldsA +
            (((uint32_t)(qrc * ROWB + h * 64 + lg * 16)) ^ qswz));

        float v[16];
        #pragma unroll
        for (int nt2 = 0; nt2 < 4; ++nt2) {
            int krow = nt2 * 16 + lr;
            if (krow > 48) krow = 48;                   // clamp (masked later)
            const bf16x8 kfr = *(const bf16x8*)((const char*)ldsB +
                (((uint32_t)(krow * ROWB + h * 64 + lg * 16)) ^ ((krow & 7) << 4)));
            f32x4 p = __builtin_amdgcn_mfma_f32_16x16x32_bf16(
                kfr, qfr, f32x4{0.f, 0.f, 0.f, 0.f}, 0, 0, 0);
            #pragma unroll
            for (int r = 0; r < 4; ++r) {
                int k = nt2 * 16 + lg * 4 + r;
                v[nt2 * 4 + r] = (k < NPIX) ? p[r] : -INFINITY;
            }
        }

        // row softmax: 16 in-lane values + 2 cross-lane steps (l^16, l^32)
        float m = v[0];
        #pragma unroll
        for (int i = 1; i < 16; ++i) m = fmaxf(m, v[i]);
        m = fmaxf(m, __shfl_xor(m, 16, 64));
        m = fmaxf(m, __shfl_xor(m, 32, 64));

        float sum = 0.f;
        #pragma unroll
        for (int i = 0; i < 16; ++i) {
            v[i] = exp2f(v[i] - m);    // logits already in log2 domain
            sum += v[i];
        }
        sum += __shfl_xor(sum, 16, 64);
        sum += __shfl_xor(sum, 32, 64);
        const float inv = __fdividef(1.0f, sum);

        if (qrow < NPIX) {
            float* orow = outw + h * (NPIX * NPIX) + qrow * NPIX;
            #pragma unroll
            for (int nt2 = 0; nt2 < 3; ++nt2)
                #pragma unroll
                for (int r = 0; r < 4; ++r)
                    orow[nt2 * 16 + lg * 4 + r] = v[nt2 * 4 + r] * inv;
            if (lg == 0) orow[48] = v[12] * inv;
        }
    };

    const int h1 = wave >> 2;      // 0..3
    do_head(h1);
    if (wave < 8) do_head(h1 + 4); // heads 4,5
}

extern "C" void kernel_launch(void* const* d_in, const int* in_sizes, int n_in,
                              void* d_out, int out_size, void* d_ws, size_t ws_size,
                              hipStream_t stream) {
    const float* x  = (const float*)d_in[0];
    const float* W  = (const float*)d_in[1];
    const float* bq = (const float*)d_in[2];
    float* out = (float*)d_out;
    uint16_t* wbf = (uint16_t*)d_ws;   // 147456 B swizzled W + 1536 B bias f32

    wconv_kernel<<<(384 * 192 + 255) / 256, 256, 0, stream>>>(W, bq, wbf);
    attn_win_kernel<<<NWIN, 1024, 0, stream>>>(x, wbf, out);
}